// Round 12
// baseline (220.542 us; speedup 1.0000x reference)
//
#include <hip/hip_runtime.h>
#include <hip/hip_bf16.h>
#include <math.h>

// ---------------------------------------------------------------------------
// FeatureNet (DGCNN edge-conv block), MI355X / gfx950, round 12.
//
// Round-12 changes:
//  * conv3 is LDS-free: y2t[p][c] p-major IS the MFMA B-frag layout, so
//    fragments load straight from global with in-reg BN2+ReLU+cast
//    (no staging, no barriers; transform 4x redundant but VALU was 27% busy).
//  * g stored as float4 p-major (g4[p]); knn writes 16B/lane, conv2 stages
//    with one b128.
// kNN / conv2 / finalize / bn3max otherwise = round-11 proven.
// ---------------------------------------------------------------------------

#define B_   16
#define N_   2048
#define KNN  8
#define DIM  128
#define P_   (B_*N_*KNN)   // 262144
#define CAP  128
#define NBLK 2048          // conv blocks (128 p each)

typedef __attribute__((ext_vector_type(8))) short bf16x8;
typedef __attribute__((ext_vector_type(4))) short bf16x4;
typedef __attribute__((ext_vector_type(4))) float f32x4;

// ws layout (bytes)
#define OFF_G     0ull
#define SZ_G      ((size_t)P_*16)              // 4,194,304 (float4 per p)
#define OFF_Y2B   (OFF_G + SZ_G)
#define SZ_Y2B    ((size_t)DIM*P_*2)           // 67,108,864  (y2t[p][c])
#define OFF_STATS (OFF_Y2B + SZ_Y2B)
#define N_STATS   4112
#define SZ_STATS  ((size_t)N_STATS*8)
#define OFF_AB    (OFF_STATS + SZ_STATS)
#define SZ_AB     4096ull
#define OFF_KPART (OFF_AB + SZ_AB)
#define NKBLK     2048
#define SZ_KPART  ((size_t)9*NKBLK*4)
#define OFF_YMM   (OFF_KPART + SZ_KPART)
#define SZ_YMM    ((size_t)DIM*NBLK*32*4)      // 33,554,432

// stats (f64) indices
#define I_S2   16
#define I_S3   (16 + 8*256)
#define NBANK  8

// ab (float) layout
#define AB_W1F 0
#define AB_A2  512
#define AB_E2  640
#define AB_A3  768
#define AB_E3  896

// DPP ctrl codes
#define DPP_XOR1   0xB1    // quad_perm [1,0,3,2]
#define DPP_XOR2   0x4E    // quad_perm [2,3,0,1]
#define DPP_HALFM  0x141   // row_half_mirror: lane ^ 7
#define DPP_MIRROR 0x140   // row_mirror: lane ^ 15

template<int C>
__device__ __forceinline__ float dppf(float v) {
    return __int_as_float(__builtin_amdgcn_update_dpp(
        __float_as_int(v), __float_as_int(v), C, 0xF, 0xF, false));
}

__device__ __forceinline__ void atomAddD(double* p, double v) {
    __hip_atomic_fetch_add(p, v, __ATOMIC_RELAXED, __HIP_MEMORY_SCOPE_AGENT);
}
__device__ __forceinline__ unsigned short f2bs(float f) {
    const unsigned b = __float_as_uint(f);
    return (unsigned short)((b + 0x7FFFu + ((b >> 16) & 1u)) >> 16);   // RNE
}
__device__ __forceinline__ float bs2f(unsigned short u) {
    return __uint_as_float(((unsigned)u) << 16);
}

// ---------------------------------------------------------------------------
// kNN + grouped offsets + layer-1 moment partials + stats zeroing (block 0,0).
__global__ __launch_bounds__(1024) void knn_group_kernel(
    const float* __restrict__ x, float4* __restrict__ g4,
    float* __restrict__ kpart, double* __restrict__ st)
{
    __shared__ __align__(16) float4 xs4[N_];           // 32 KB {x,y,z,|x|^2}
    __shared__ unsigned long long listK[16][CAP];      // 16 KB packed keys
    __shared__ float spart[16][12];
    const int b   = blockIdx.y;
    const int tid = threadIdx.x;
    const int wv  = tid >> 6;
    const int ln  = tid & 63;
    const int n   = blockIdx.x * 16 + wv;
    const float* xb = x + (size_t)b * 3 * N_;

    if (blockIdx.x == 0 && blockIdx.y == 0)
        for (int i = tid; i < N_STATS; i += 1024) st[i] = 0.0;

    for (int i = tid; i < N_; i += 1024) {
        const float a0 = xb[i], a1 = xb[N_ + i], a2 = xb[2*N_ + i];
        const float sq = __fadd_rn(__fadd_rn(__fmul_rn(a0,a0), __fmul_rn(a1,a1)), __fmul_rn(a2,a2));
        xs4[i] = make_float4(a0, a1, a2, sq);
    }
    __syncthreads();

    const float4 me = xs4[n];
    const float xn0 = me.x, xn1 = me.y, xn2 = me.z, sqn = me.w;

    // ---- Pass A
    float dreg[32];
    float lmin = INFINITY;
    #pragma unroll
    for (int i = 0; i < 32; ++i) {
        const float4 q = xs4[ln + 64*i];
        dreg[i] = __fadd_rn(__fmaf_rn(-2.f, __fmaf_rn(xn2, q.z, __fmaf_rn(xn1, q.y, __fmul_rn(xn0, q.x))), sqn), q.w);
        lmin = fminf(lmin, dreg[i]);
    }

    // ---- bound B' = max over 8 groups of (min over each 8-lane group)
    float gm = lmin;
    gm = fminf(gm, __shfl_xor(gm, 1));
    gm = fminf(gm, __shfl_xor(gm, 2));
    gm = fminf(gm, __shfl_xor(gm, 4));
    float Bb = gm;
    Bb = fmaxf(Bb, __shfl_xor(Bb, 8));
    Bb = fmaxf(Bb, __shfl_xor(Bb, 16));
    Bb = fmaxf(Bb, __shfl_xor(Bb, 32));

    // ---- Pass B: ballot-compact packed keys (orderable(d)<<32 | idx)
    unsigned base = 0;
    #pragma unroll
    for (int i = 0; i < 32; ++i) {
        const bool pred = (dreg[i] <= Bb);
        const unsigned long long mk = __ballot(pred);
        if (pred) {
            const unsigned pos = base + (unsigned)__popcll(mk & ((1ull << ln) - 1ull));
            if (pos < CAP) {
                const unsigned u = __float_as_uint(dreg[i]);
                const unsigned od = u ^ ((unsigned)(((int)u) >> 31) | 0x80000000u);
                listK[wv][pos] = (((unsigned long long)od) << 32) | (unsigned)(ln + 64*i);
            }
        }
        base += (unsigned)__popcll(mk);
    }
    const int cnt = (base < CAP) ? (int)base : CAP;

    // ---- Pass C: exact top-8 selection (lex (d,idx) == lax.top_k order)
    int myi = 0;
    if (cnt <= 64) {
        unsigned long long K = (ln < cnt) ? listK[wv][ln] : ~0ull;
        #pragma unroll
        for (int k = 2; k <= 64; k <<= 1) {
            #pragma unroll
            for (int j = k >> 1; j >= 1; j >>= 1) {
                const unsigned long long o = __shfl_xor(K, j);
                const bool takeMin = (((ln & j) == 0) == ((ln & k) == 0));
                const bool oLess = (o < K);
                if (takeMin ? oLess : !oLess) K = o;
            }
        }
        myi = (int)(unsigned)K;
    } else {
        unsigned long long K0 = (ln < cnt)      ? listK[wv][ln]      : ~0ull;
        unsigned long long K1 = (ln + 64 < cnt) ? listK[wv][ln + 64] : ~0ull;
        #pragma unroll
        for (int sel = 0; sel < 8; ++sel) {
            unsigned long long p = (K1 < K0) ? K1 : K0;
            #pragma unroll
            for (int m = 1; m < 64; m <<= 1) {
                const unsigned long long o = __shfl_xor(p, m);
                if (o < p) p = o;
            }
            if (ln == sel) myi = (int)(unsigned)p;
            if (K0 == p) K0 = ~0ull;
            if (K1 == p) K1 = ~0ull;
        }
    }

    // ---- gather, g4-write, stats (lanes 0..7 hold the 8 neighbors)
    if (ln < 8) {
        const float4 q = xs4[myi];
        const float g0  = q.x - xn0;
        const float g1v = q.y - xn1;
        const float g2v = q.z - xn2;
        g4[((size_t)b*N_ + n)*KNN + ln] = make_float4(g0, g1v, g2v, 0.f);
        float s0 = g0, s1 = g1v, s2 = g2v;
        float s00 = g0*g0, s01 = g0*g1v, s02 = g0*g2v;
        float s11 = g1v*g1v, s12 = g1v*g2v, s22 = g2v*g2v;
        #pragma unroll
        for (int m = 1; m < 8; m <<= 1) {
            s0 += __shfl_xor(s0, m);  s1 += __shfl_xor(s1, m);  s2 += __shfl_xor(s2, m);
            s00 += __shfl_xor(s00, m); s01 += __shfl_xor(s01, m); s02 += __shfl_xor(s02, m);
            s11 += __shfl_xor(s11, m); s12 += __shfl_xor(s12, m); s22 += __shfl_xor(s22, m);
        }
        if (ln == 0) {
            spart[wv][0] = s0;  spart[wv][1] = s1;  spart[wv][2] = s2;
            spart[wv][3] = s00; spart[wv][4] = s01; spart[wv][5] = s02;
            spart[wv][6] = s11; spart[wv][7] = s12; spart[wv][8] = s22;
        }
    }
    __syncthreads();
    if (tid < 9) {
        float a = 0.f;
        #pragma unroll
        for (int w = 0; w < 16; ++w) a += spart[w][tid];
        kpart[tid*NKBLK + blockIdx.y*128 + blockIdx.x] = a;
    }
}

// ---------------------------------------------------------------------------
__global__ __launch_bounds__(1024) void finalize1_kernel(
    const float* __restrict__ kpart, const float* __restrict__ W1,
    const float* __restrict__ b1, const float* __restrict__ g1,
    const float* __restrict__ be1, float* __restrict__ ab)
{
    __shared__ double S9[9];
    const int tid = threadIdx.x;
    const int w = tid >> 6, l = tid & 63;
    if (w < 9) {
        double a = 0.0;
        #pragma unroll
        for (int i = 0; i < 32; ++i) a += (double)kpart[w*NKBLK + l + 64*i];
        #pragma unroll
        for (int m = 1; m < 64; m <<= 1) a += __shfl_xor(a, m);
        if (l == 0) S9[w] = a;
    }
    __syncthreads();
    if (tid < 128) {
        const int d = tid;
        const double inv = 1.0 / (double)P_;
        const double mu0 = S9[0]*inv, mu1 = S9[1]*inv, mu2 = S9[2]*inv;
        const double c00 = S9[3]*inv - mu0*mu0;
        const double c01 = S9[4]*inv - mu0*mu1;
        const double c02 = S9[5]*inv - mu0*mu2;
        const double c11 = S9[6]*inv - mu1*mu1;
        const double c12 = S9[7]*inv - mu1*mu2;
        const double c22 = S9[8]*inv - mu2*mu2;
        const double w0 = W1[d*3+0], w1 = W1[d*3+1], w2 = W1[d*3+2];
        const double mean = w0*mu0 + w1*mu1 + w2*mu2 + (double)b1[d];
        double var = w0*w0*c00 + w1*w1*c11 + w2*w2*c22
                   + 2.0*(w0*w1*c01 + w0*w2*c02 + w1*w2*c12);
        if (var < 0.0) var = 0.0;
        const double r = 1.0 / sqrt(var + 1e-5);
        const double alpha = (double)g1[d] * r;
        const double beta  = (double)be1[d] - mean*alpha;
        ab[AB_W1F + 4*d + 0] = (float)(alpha * w0);
        ab[AB_W1F + 4*d + 1] = (float)(alpha * w1);
        ab[AB_W1F + 4*d + 2] = (float)(alpha * w2);
        ab[AB_W1F + 4*d + 3] = (float)(alpha * (double)b1[d] + beta);
    }
}

__global__ void finalize23_kernel(
    const double* __restrict__ st, int soff,
    const float* __restrict__ gg, const float* __restrict__ bee,
    float* __restrict__ ab, int aoff)
{
    const int d = threadIdx.x;
    if (d >= DIM) return;
    double s1 = 0.0, s2 = 0.0;
    #pragma unroll
    for (int k = 0; k < NBANK; ++k) {
        s1 += st[soff + k*256 + d];
        s2 += st[soff + k*256 + 128 + d];
    }
    const double inv = 1.0 / (double)P_;
    const double mean = s1 * inv;
    double var = s2 * inv - mean*mean;
    if (var < 0.0) var = 0.0;
    const double r = 1.0 / sqrt(var + 1e-5);
    const double alpha = (double)gg[d] * r;
    ab[aoff + d]       = (float)alpha;
    ab[aoff + 128 + d] = (float)((double)bee[d] - mean*alpha);
}

// ---------------------------------------------------------------------------
// conv2 (r11 proven structure): 128d x 128p, 4 waves, LDS-staged H from g4,
// MFMA, DPP stats, LDS transpose -> coalesced p-major bf16 y2t stores.
__global__ __launch_bounds__(256) void conv2_kernel(
    const float4* __restrict__ g4, const float* __restrict__ Wf,
    const float* __restrict__ ab, const float* __restrict__ bias,
    unsigned short* __restrict__ ybdst, double* __restrict__ stats)
{
    __shared__ __align__(16) short Hs[128*136];
    const int tid = threadIdx.x;
    const int p0g = blockIdx.x * 128;
    const int w  = tid >> 6, ln = tid & 63;
    const int lg = ln >> 4, lr = ln & 15;

    bf16x8 afrag[2][4];
    #pragma unroll
    for (int dtl = 0; dtl < 2; ++dtl)
        #pragma unroll
        for (int ks = 0; ks < 4; ++ks) {
            const float* wr = &Wf[(size_t)(32*w + 16*dtl + lr)*DIM + (4*ks + lg)*8];
            const float4 a4 = *(const float4*)wr;
            const float4 b4 = *(const float4*)(wr + 4);
            bf16x8 f;
            f[0]=(short)f2bs(a4.x); f[1]=(short)f2bs(a4.y); f[2]=(short)f2bs(a4.z); f[3]=(short)f2bs(a4.w);
            f[4]=(short)f2bs(b4.x); f[5]=(short)f2bs(b4.y); f[6]=(short)f2bs(b4.z); f[7]=(short)f2bs(b4.w);
            afrag[dtl][ks] = f;
        }

    {
        const int sp = 64*(w & 1) + ln;     // 0..127
        const int ob = w >> 1;              // 0 or 1
        const float4 gq = g4[p0g + sp];
        #pragma unroll
        for (int it = 0; it < 8; ++it) {
            const int o = ob + 2*it;
            bf16x8 hv;
            #pragma unroll
            for (int j = 0; j < 8; ++j) {
                const int c = 8*o + j;
                const float4 wf = *(const float4*)&ab[AB_W1F + 4*c];
                const float h = fmaxf(__fmaf_rn(wf.x, gq.x, __fmaf_rn(wf.y, gq.y, __fmaf_rn(wf.z, gq.z, wf.w))), 0.f);
                hv[j] = (short)f2bs(h);
            }
            *(bf16x8*)&Hs[sp*128 + ((o ^ (sp & 7)) * 8)] = hv;
        }
    }
    __syncthreads();

    f32x4 acc[2][8];
    #pragma unroll
    for (int i = 0; i < 2; ++i)
        #pragma unroll
        for (int j = 0; j < 8; ++j)
            acc[i][j] = (f32x4){0.f, 0.f, 0.f, 0.f};

    #pragma unroll
    for (int ks = 0; ks < 4; ++ks) {
        #pragma unroll
        for (int pt = 0; pt < 8; ++pt) {
            const int p = 16*pt + lr;
            const bf16x8 bf = *(const bf16x8*)&Hs[p*128 + (((4*ks + lg) ^ (lr & 7)) * 8)];
            acc[0][pt] = __builtin_amdgcn_mfma_f32_16x16x32_bf16(afrag[0][ks], bf, acc[0][pt], 0, 0, 0);
            acc[1][pt] = __builtin_amdgcn_mfma_f32_16x16x32_bf16(afrag[1][ks], bf, acc[1][pt], 0, 0, 0);
        }
    }

    const int bank = blockIdx.x & (NBANK-1);
    #pragma unroll
    for (int dtl = 0; dtl < 2; ++dtl) {
        #pragma unroll
        for (int r = 0; r < 4; ++r) {
            const int d = 32*w + 16*dtl + 4*lg + r;
            const float bb = bias[d];
            float v[8];
            #pragma unroll
            for (int pt = 0; pt < 8; ++pt) v[pt] = acc[dtl][pt][r] + bb;
            float s1 = ((v[0]+v[1])+(v[2]+v[3])) + ((v[4]+v[5])+(v[6]+v[7]));
            float s2 = ((v[0]*v[0]+v[1]*v[1])+(v[2]*v[2]+v[3]*v[3]))
                     + ((v[4]*v[4]+v[5]*v[5])+(v[6]*v[6]+v[7]*v[7]));
            s1 += dppf<DPP_XOR1>(s1);  s2 += dppf<DPP_XOR1>(s2);
            s1 += dppf<DPP_XOR2>(s1);  s2 += dppf<DPP_XOR2>(s2);
            s1 += dppf<DPP_HALFM>(s1); s2 += dppf<DPP_HALFM>(s2);
            s1 += dppf<DPP_MIRROR>(s1); s2 += dppf<DPP_MIRROR>(s2);
            if (lr == 0) {
                atomAddD(&stats[I_S2 + bank*256 + d], (double)s1);
                atomAddD(&stats[I_S2 + bank*256 + 128 + d], (double)s2);
            }
        }
    }

    // ---- LDS transpose -> fully coalesced p-major stores
    __syncthreads();
    #pragma unroll
    for (int dtl = 0; dtl < 2; ++dtl) {
        const int d0 = 32*w + 16*dtl + 4*lg;
        const float4 b4 = *(const float4*)&bias[d0];
        #pragma unroll
        for (int pt = 0; pt < 8; ++pt) {
            const int p = 16*pt + lr;
            bf16x4 pk;
            pk[0] = (short)f2bs(acc[dtl][pt][0] + b4.x);
            pk[1] = (short)f2bs(acc[dtl][pt][1] + b4.y);
            pk[2] = (short)f2bs(acc[dtl][pt][2] + b4.z);
            pk[3] = (short)f2bs(acc[dtl][pt][3] + b4.w);
            *(bf16x4*)&Hs[p*136 + d0] = pk;
        }
    }
    __syncthreads();
    #pragma unroll
    for (int it = 0; it < 8; ++it) {
        const int f = it*256 + tid;
        const int row = f >> 4, ch = f & 15;
        const bf16x8 vv = *(const bf16x8*)&Hs[row*136 + ch*8];
        *(bf16x8*)&ybdst[(size_t)(p0g + row)*128 + ch*8] = vv;
    }
}

// ---------------------------------------------------------------------------
// conv3: LDS-free. y2t[p][c] p-major == B-frag layout; load 16B/lane direct,
// BN2+ReLU+bf16 in registers. No barriers. DPP stats + minmax -> ymm.
__global__ __launch_bounds__(256) void conv3_kernel(
    const unsigned short* __restrict__ ybsrc, const float* __restrict__ Wf,
    const float* __restrict__ ab, const float* __restrict__ bias,
    float* __restrict__ ymm, double* __restrict__ stats)
{
    const int tid = threadIdx.x;
    const int p0g = blockIdx.x * 128;
    const int w  = tid >> 6, ln = tid & 63;
    const int lg = ln >> 4, lr = ln & 15;

    bf16x8 afrag[2][4];
    #pragma unroll
    for (int dtl = 0; dtl < 2; ++dtl)
        #pragma unroll
        for (int ks = 0; ks < 4; ++ks) {
            const float* wr = &Wf[(size_t)(32*w + 16*dtl + lr)*DIM + (4*ks + lg)*8];
            const float4 a4 = *(const float4*)wr;
            const float4 b4 = *(const float4*)(wr + 4);
            bf16x8 f;
            f[0]=(short)f2bs(a4.x); f[1]=(short)f2bs(a4.y); f[2]=(short)f2bs(a4.z); f[3]=(short)f2bs(a4.w);
            f[4]=(short)f2bs(b4.x); f[5]=(short)f2bs(b4.y); f[6]=(short)f2bs(b4.z); f[7]=(short)f2bs(b4.w);
            afrag[dtl][ks] = f;
        }

    f32x4 acc[2][8];
    #pragma unroll
    for (int i = 0; i < 2; ++i)
        #pragma unroll
        for (int j = 0; j < 8; ++j)
            acc[i][j] = (f32x4){0.f, 0.f, 0.f, 0.f};

    #pragma unroll
    for (int ks = 0; ks < 4; ++ks) {
        const int o = 4*ks + lg;            // this lane's c-octet for this ks
        const float4 aLo = *(const float4*)&ab[AB_A2 + o*8];
        const float4 aHi = *(const float4*)&ab[AB_A2 + o*8 + 4];
        const float4 eLo = *(const float4*)&ab[AB_E2 + o*8];
        const float4 eHi = *(const float4*)&ab[AB_E2 + o*8 + 4];
        const float av[8] = {aLo.x,aLo.y,aLo.z,aLo.w,aHi.x,aHi.y,aHi.z,aHi.w};
        const float ev[8] = {eLo.x,eLo.y,eLo.z,eLo.w,eHi.x,eHi.y,eHi.z,eHi.w};
        #pragma unroll
        for (int pt = 0; pt < 8; ++pt) {
            const bf16x8 raw = *(const bf16x8*)&ybsrc[(size_t)(p0g + 16*pt + lr)*128 + o*8];
            bf16x8 bf;
            #pragma unroll
            for (int j = 0; j < 8; ++j) {
                const float v = bs2f((unsigned short)raw[j]);
                bf[j] = (short)f2bs(fmaxf(__fmaf_rn(av[j], v, ev[j]), 0.f));
            }
            acc[0][pt] = __builtin_amdgcn_mfma_f32_16x16x32_bf16(afrag[0][ks], bf, acc[0][pt], 0, 0, 0);
            acc[1][pt] = __builtin_amdgcn_mfma_f32_16x16x32_bf16(afrag[1][ks], bf, acc[1][pt], 0, 0, 0);
        }
    }

    const int bank = blockIdx.x & (NBANK-1);
    #pragma unroll
    for (int dtl = 0; dtl < 2; ++dtl) {
        #pragma unroll
        for (int r = 0; r < 4; ++r) {
            const int d = 32*w + 16*dtl + 4*lg + r;
            const float bb = bias[d];
            float v[8];
            #pragma unroll
            for (int pt = 0; pt < 8; ++pt) v[pt] = acc[dtl][pt][r] + bb;

            float s1 = ((v[0]+v[1])+(v[2]+v[3])) + ((v[4]+v[5])+(v[6]+v[7]));
            float s2 = ((v[0]*v[0]+v[1]*v[1])+(v[2]*v[2]+v[3]*v[3]))
                     + ((v[4]*v[4]+v[5]*v[5])+(v[6]*v[6]+v[7]*v[7]));
            s1 += dppf<DPP_XOR1>(s1);  s2 += dppf<DPP_XOR1>(s2);
            s1 += dppf<DPP_XOR2>(s1);  s2 += dppf<DPP_XOR2>(s2);
            s1 += dppf<DPP_HALFM>(s1); s2 += dppf<DPP_HALFM>(s2);
            s1 += dppf<DPP_MIRROR>(s1); s2 += dppf<DPP_MIRROR>(s2);
            if (lr == 0) {
                atomAddD(&stats[I_S3 + bank*256 + d], (double)s1);
                atomAddD(&stats[I_S3 + bank*256 + 128 + d], (double)s2);
            }

            #pragma unroll
            for (int pt = 0; pt < 8; ++pt) {
                float mx = v[pt], mn = v[pt];
                mx = fmaxf(mx, dppf<DPP_XOR1>(mx));  mn = fminf(mn, dppf<DPP_XOR1>(mn));
                mx = fmaxf(mx, dppf<DPP_XOR2>(mx));  mn = fminf(mn, dppf<DPP_XOR2>(mn));
                mx = fmaxf(mx, dppf<DPP_HALFM>(mx)); mn = fminf(mn, dppf<DPP_HALFM>(mn));
                if ((lr & 7) == 0) {
                    const int slot = 2*pt + (lr >> 3);
                    float* yb = ymm + ((size_t)d*NBLK + blockIdx.x)*32;
                    yb[slot]      = mx;
                    yb[16 + slot] = mn;
                }
            }
        }
    }
}

// ---------------------------------------------------------------------------
// Epilogue: out[b,d,n] = relu(a3*(a3>=0 ? max_k : min_k) + e3)
__global__ __launch_bounds__(256) void bn3max_kernel(
    const float* __restrict__ ymm, const float* __restrict__ ab, float* __restrict__ out)
{
    const int idx = blockIdx.x*256 + threadIdx.x;   // over B*DIM*N
    const int n = idx & (N_-1);
    const int d = (idx >> 11) & (DIM-1);
    const int b = idx >> 18;
    const int pt  = b*N_ + n;
    const int blk = pt >> 4;
    const int j   = pt & 15;
    const size_t base = ((size_t)d*NBLK + blk) * 32;
    const float a = ab[AB_A3 + d], e = ab[AB_E3 + d];
    const float mx = ymm[base + j];
    const float mn = ymm[base + 16 + j];
    const float v = (a >= 0.f) ? mx : mn;
    out[idx] = fmaxf(__fmaf_rn(a, v, e), 0.f);
}

// ---------------------------------------------------------------------------
extern "C" void kernel_launch(void* const* d_in, const int* in_sizes, int n_in,
                              void* d_out, int out_size, void* d_ws, size_t ws_size,
                              hipStream_t stream) {
    (void)in_sizes; (void)n_in; (void)out_size; (void)ws_size;
    const float* x   = (const float*)d_in[0];
    const float* W1  = (const float*)d_in[1];
    const float* b1  = (const float*)d_in[2];
    const float* g1  = (const float*)d_in[3];
    const float* be1 = (const float*)d_in[4];
    const float* W2  = (const float*)d_in[5];
    const float* b2  = (const float*)d_in[6];
    const float* g2  = (const float*)d_in[7];
    const float* be2 = (const float*)d_in[8];
    const float* W3  = (const float*)d_in[9];
    const float* b3  = (const float*)d_in[10];
    const float* g3  = (const float*)d_in[11];
    const float* be3 = (const float*)d_in[12];

    float*  out = (float*)d_out;
    char*   ws  = (char*)d_ws;
    float4*         g4  = (float4*)(ws + OFF_G);
    unsigned short* y2t = (unsigned short*)(ws + OFF_Y2B);
    double*         st  = (double*)(ws + OFF_STATS);
    float*          ab  = (float*)(ws + OFF_AB);
    float*          kp  = (float*)(ws + OFF_KPART);
    float*          ymm = (float*)(ws + OFF_YMM);

    knn_group_kernel<<<dim3(128, B_), 1024, 0, stream>>>(x, g4, kp, st);
    finalize1_kernel<<<1, 1024, 0, stream>>>(kp, W1, b1, g1, be1, ab);
    conv2_kernel<<<NBLK, 256, 0, stream>>>(g4, W2, ab, b2, y2t, st);
    finalize23_kernel<<<1, 128, 0, stream>>>(st, I_S2, g2, be2, ab, AB_A2);
    conv3_kernel<<<NBLK, 256, 0, stream>>>(y2t, W3, ab, b3, ymm, st);
    finalize23_kernel<<<1, 128, 0, stream>>>(st, I_S3, g3, be3, ab, AB_A3);
    bn3max_kernel<<<(B_*DIM*N_)/256, 256, 0, stream>>>(ymm, ab, out);
}

// Round 13
// 206.044 us; speedup vs baseline: 1.0704x; 1.0704x over previous
//
#include <hip/hip_runtime.h>
#include <hip/hip_bf16.h>
#include <math.h>

// ---------------------------------------------------------------------------
// FeatureNet (DGCNN edge-conv block), MI355X / gfx950, round 13.
//
// Round-13 change: y2 is never materialized in global memory.
//  * conv2stats: conv2 staging+MFMA (r11-proven), epilogue = DPP stats2 only.
//  * convfused : recompute y2 (bit-identical path), BN2+ReLU in-LDS
//    (h2 written back into the same swizzled [p][c] buffer), reload A-frags
//    with W3, second MFMA, then r11-proven stats3 + minmax -> ymm epilogue.
//  Kills the 134MB y2 round trip (convs were HBM-bound at ~1.2 TB/s).
// kNN / finalize / bn3max = round-12 proven versions.
// ---------------------------------------------------------------------------

#define B_   16
#define N_   2048
#define KNN  8
#define DIM  128
#define P_   (B_*N_*KNN)   // 262144
#define CAP  128
#define NBLK 2048          // conv blocks (128 p each)

typedef __attribute__((ext_vector_type(8))) short bf16x8;
typedef __attribute__((ext_vector_type(4))) short bf16x4;
typedef __attribute__((ext_vector_type(4))) float f32x4;

// ws layout (bytes)
#define OFF_G     0ull
#define SZ_G      ((size_t)P_*16)              // 4,194,304 (float4 per p)
#define OFF_STATS (OFF_G + SZ_G)
#define N_STATS   4112
#define SZ_STATS  ((size_t)N_STATS*8)
#define OFF_AB    (OFF_STATS + SZ_STATS)
#define SZ_AB     4096ull
#define OFF_KPART (OFF_AB + SZ_AB)
#define NKBLK     2048
#define SZ_KPART  ((size_t)9*NKBLK*4)
#define OFF_YMM   (OFF_KPART + SZ_KPART)
#define SZ_YMM    ((size_t)DIM*NBLK*32*4)      // 33,554,432

// stats (f64) indices
#define I_S2   16
#define I_S3   (16 + 8*256)
#define NBANK  8

// ab (float) layout
#define AB_W1F 0
#define AB_A2  512
#define AB_E2  640
#define AB_A3  768
#define AB_E3  896

// DPP ctrl codes
#define DPP_XOR1   0xB1    // quad_perm [1,0,3,2]
#define DPP_XOR2   0x4E    // quad_perm [2,3,0,1]
#define DPP_HALFM  0x141   // row_half_mirror: lane ^ 7
#define DPP_MIRROR 0x140   // row_mirror: lane ^ 15

template<int C>
__device__ __forceinline__ float dppf(float v) {
    return __int_as_float(__builtin_amdgcn_update_dpp(
        __float_as_int(v), __float_as_int(v), C, 0xF, 0xF, false));
}

__device__ __forceinline__ void atomAddD(double* p, double v) {
    __hip_atomic_fetch_add(p, v, __ATOMIC_RELAXED, __HIP_MEMORY_SCOPE_AGENT);
}
__device__ __forceinline__ unsigned short f2bs(float f) {
    const unsigned b = __float_as_uint(f);
    return (unsigned short)((b + 0x7FFFu + ((b >> 16) & 1u)) >> 16);   // RNE
}
__device__ __forceinline__ float bs2f(unsigned short u) {
    return __uint_as_float(((unsigned)u) << 16);
}

// ---------------------------------------------------------------------------
// kNN + grouped offsets + layer-1 moment partials + stats zeroing (block 0,0).
__global__ __launch_bounds__(1024) void knn_group_kernel(
    const float* __restrict__ x, float4* __restrict__ g4,
    float* __restrict__ kpart, double* __restrict__ st)
{
    __shared__ __align__(16) float4 xs4[N_];           // 32 KB {x,y,z,|x|^2}
    __shared__ unsigned long long listK[16][CAP];      // 16 KB packed keys
    __shared__ float spart[16][12];
    const int b   = blockIdx.y;
    const int tid = threadIdx.x;
    const int wv  = tid >> 6;
    const int ln  = tid & 63;
    const int n   = blockIdx.x * 16 + wv;
    const float* xb = x + (size_t)b * 3 * N_;

    if (blockIdx.x == 0 && blockIdx.y == 0)
        for (int i = tid; i < N_STATS; i += 1024) st[i] = 0.0;

    for (int i = tid; i < N_; i += 1024) {
        const float a0 = xb[i], a1 = xb[N_ + i], a2 = xb[2*N_ + i];
        const float sq = __fadd_rn(__fadd_rn(__fmul_rn(a0,a0), __fmul_rn(a1,a1)), __fmul_rn(a2,a2));
        xs4[i] = make_float4(a0, a1, a2, sq);
    }
    __syncthreads();

    const float4 me = xs4[n];
    const float xn0 = me.x, xn1 = me.y, xn2 = me.z, sqn = me.w;

    // ---- Pass A
    float dreg[32];
    float lmin = INFINITY;
    #pragma unroll
    for (int i = 0; i < 32; ++i) {
        const float4 q = xs4[ln + 64*i];
        dreg[i] = __fadd_rn(__fmaf_rn(-2.f, __fmaf_rn(xn2, q.z, __fmaf_rn(xn1, q.y, __fmul_rn(xn0, q.x))), sqn), q.w);
        lmin = fminf(lmin, dreg[i]);
    }

    // ---- bound B' = max over 8 groups of (min over each 8-lane group)
    float gm = lmin;
    gm = fminf(gm, __shfl_xor(gm, 1));
    gm = fminf(gm, __shfl_xor(gm, 2));
    gm = fminf(gm, __shfl_xor(gm, 4));
    float Bb = gm;
    Bb = fmaxf(Bb, __shfl_xor(Bb, 8));
    Bb = fmaxf(Bb, __shfl_xor(Bb, 16));
    Bb = fmaxf(Bb, __shfl_xor(Bb, 32));

    // ---- Pass B: ballot-compact packed keys (orderable(d)<<32 | idx)
    unsigned base = 0;
    #pragma unroll
    for (int i = 0; i < 32; ++i) {
        const bool pred = (dreg[i] <= Bb);
        const unsigned long long mk = __ballot(pred);
        if (pred) {
            const unsigned pos = base + (unsigned)__popcll(mk & ((1ull << ln) - 1ull));
            if (pos < CAP) {
                const unsigned u = __float_as_uint(dreg[i]);
                const unsigned od = u ^ ((unsigned)(((int)u) >> 31) | 0x80000000u);
                listK[wv][pos] = (((unsigned long long)od) << 32) | (unsigned)(ln + 64*i);
            }
        }
        base += (unsigned)__popcll(mk);
    }
    const int cnt = (base < CAP) ? (int)base : CAP;

    // ---- Pass C: exact top-8 selection (lex (d,idx) == lax.top_k order)
    int myi = 0;
    if (cnt <= 64) {
        unsigned long long K = (ln < cnt) ? listK[wv][ln] : ~0ull;
        #pragma unroll
        for (int k = 2; k <= 64; k <<= 1) {
            #pragma unroll
            for (int j = k >> 1; j >= 1; j >>= 1) {
                const unsigned long long o = __shfl_xor(K, j);
                const bool takeMin = (((ln & j) == 0) == ((ln & k) == 0));
                const bool oLess = (o < K);
                if (takeMin ? oLess : !oLess) K = o;
            }
        }
        myi = (int)(unsigned)K;
    } else {
        unsigned long long K0 = (ln < cnt)      ? listK[wv][ln]      : ~0ull;
        unsigned long long K1 = (ln + 64 < cnt) ? listK[wv][ln + 64] : ~0ull;
        #pragma unroll
        for (int sel = 0; sel < 8; ++sel) {
            unsigned long long p = (K1 < K0) ? K1 : K0;
            #pragma unroll
            for (int m = 1; m < 64; m <<= 1) {
                const unsigned long long o = __shfl_xor(p, m);
                if (o < p) p = o;
            }
            if (ln == sel) myi = (int)(unsigned)p;
            if (K0 == p) K0 = ~0ull;
            if (K1 == p) K1 = ~0ull;
        }
    }

    // ---- gather, g4-write, stats (lanes 0..7 hold the 8 neighbors)
    if (ln < 8) {
        const float4 q = xs4[myi];
        const float g0  = q.x - xn0;
        const float g1v = q.y - xn1;
        const float g2v = q.z - xn2;
        g4[((size_t)b*N_ + n)*KNN + ln] = make_float4(g0, g1v, g2v, 0.f);
        float s0 = g0, s1 = g1v, s2 = g2v;
        float s00 = g0*g0, s01 = g0*g1v, s02 = g0*g2v;
        float s11 = g1v*g1v, s12 = g1v*g2v, s22 = g2v*g2v;
        #pragma unroll
        for (int m = 1; m < 8; m <<= 1) {
            s0 += __shfl_xor(s0, m);  s1 += __shfl_xor(s1, m);  s2 += __shfl_xor(s2, m);
            s00 += __shfl_xor(s00, m); s01 += __shfl_xor(s01, m); s02 += __shfl_xor(s02, m);
            s11 += __shfl_xor(s11, m); s12 += __shfl_xor(s12, m); s22 += __shfl_xor(s22, m);
        }
        if (ln == 0) {
            spart[wv][0] = s0;  spart[wv][1] = s1;  spart[wv][2] = s2;
            spart[wv][3] = s00; spart[wv][4] = s01; spart[wv][5] = s02;
            spart[wv][6] = s11; spart[wv][7] = s12; spart[wv][8] = s22;
        }
    }
    __syncthreads();
    if (tid < 9) {
        float a = 0.f;
        #pragma unroll
        for (int w = 0; w < 16; ++w) a += spart[w][tid];
        kpart[tid*NKBLK + blockIdx.y*128 + blockIdx.x] = a;
    }
}

// ---------------------------------------------------------------------------
__global__ __launch_bounds__(1024) void finalize1_kernel(
    const float* __restrict__ kpart, const float* __restrict__ W1,
    const float* __restrict__ b1, const float* __restrict__ g1,
    const float* __restrict__ be1, float* __restrict__ ab)
{
    __shared__ double S9[9];
    const int tid = threadIdx.x;
    const int w = tid >> 6, l = tid & 63;
    if (w < 9) {
        double a = 0.0;
        #pragma unroll
        for (int i = 0; i < 32; ++i) a += (double)kpart[w*NKBLK + l + 64*i];
        #pragma unroll
        for (int m = 1; m < 64; m <<= 1) a += __shfl_xor(a, m);
        if (l == 0) S9[w] = a;
    }
    __syncthreads();
    if (tid < 128) {
        const int d = tid;
        const double inv = 1.0 / (double)P_;
        const double mu0 = S9[0]*inv, mu1 = S9[1]*inv, mu2 = S9[2]*inv;
        const double c00 = S9[3]*inv - mu0*mu0;
        const double c01 = S9[4]*inv - mu0*mu1;
        const double c02 = S9[5]*inv - mu0*mu2;
        const double c11 = S9[6]*inv - mu1*mu1;
        const double c12 = S9[7]*inv - mu1*mu2;
        const double c22 = S9[8]*inv - mu2*mu2;
        const double w0 = W1[d*3+0], w1 = W1[d*3+1], w2 = W1[d*3+2];
        const double mean = w0*mu0 + w1*mu1 + w2*mu2 + (double)b1[d];
        double var = w0*w0*c00 + w1*w1*c11 + w2*w2*c22
                   + 2.0*(w0*w1*c01 + w0*w2*c02 + w1*w2*c12);
        if (var < 0.0) var = 0.0;
        const double r = 1.0 / sqrt(var + 1e-5);
        const double alpha = (double)g1[d] * r;
        const double beta  = (double)be1[d] - mean*alpha;
        ab[AB_W1F + 4*d + 0] = (float)(alpha * w0);
        ab[AB_W1F + 4*d + 1] = (float)(alpha * w1);
        ab[AB_W1F + 4*d + 2] = (float)(alpha * w2);
        ab[AB_W1F + 4*d + 3] = (float)(alpha * (double)b1[d] + beta);
    }
}

__global__ void finalize23_kernel(
    const double* __restrict__ st, int soff,
    const float* __restrict__ gg, const float* __restrict__ bee,
    float* __restrict__ ab, int aoff)
{
    const int d = threadIdx.x;
    if (d >= DIM) return;
    double s1 = 0.0, s2 = 0.0;
    #pragma unroll
    for (int k = 0; k < NBANK; ++k) {
        s1 += st[soff + k*256 + d];
        s2 += st[soff + k*256 + 128 + d];
    }
    const double inv = 1.0 / (double)P_;
    const double mean = s1 * inv;
    double var = s2 * inv - mean*mean;
    if (var < 0.0) var = 0.0;
    const double r = 1.0 / sqrt(var + 1e-5);
    const double alpha = (double)gg[d] * r;
    ab[aoff + d]       = (float)alpha;
    ab[aoff + 128 + d] = (float)((double)bee[d] - mean*alpha);
}

// ---------------------------------------------------------------------------
// Shared pieces for the conv kernels.
__device__ __forceinline__ void load_afrag(
    bf16x8 (&afrag)[2][4], const float* __restrict__ Wf, int w, int lg, int lr)
{
    #pragma unroll
    for (int dtl = 0; dtl < 2; ++dtl)
        #pragma unroll
        for (int ks = 0; ks < 4; ++ks) {
            const float* wr = &Wf[(size_t)(32*w + 16*dtl + lr)*DIM + (4*ks + lg)*8];
            const float4 a4 = *(const float4*)wr;
            const float4 b4 = *(const float4*)(wr + 4);
            bf16x8 f;
            f[0]=(short)f2bs(a4.x); f[1]=(short)f2bs(a4.y); f[2]=(short)f2bs(a4.z); f[3]=(short)f2bs(a4.w);
            f[4]=(short)f2bs(b4.x); f[5]=(short)f2bs(b4.y); f[6]=(short)f2bs(b4.z); f[7]=(short)f2bs(b4.w);
            afrag[dtl][ks] = f;
        }
}

__device__ __forceinline__ void stage_h1(
    short* Hs, const float4* __restrict__ g4, const float* __restrict__ ab,
    int p0g, int w, int ln)
{
    const int sp = 64*(w & 1) + ln;     // 0..127
    const int ob = w >> 1;              // 0 or 1
    const float4 gq = g4[p0g + sp];
    #pragma unroll
    for (int it = 0; it < 8; ++it) {
        const int o = ob + 2*it;
        bf16x8 hv;
        #pragma unroll
        for (int j = 0; j < 8; ++j) {
            const int c = 8*o + j;
            const float4 wf = *(const float4*)&ab[AB_W1F + 4*c];
            const float h = fmaxf(__fmaf_rn(wf.x, gq.x, __fmaf_rn(wf.y, gq.y, __fmaf_rn(wf.z, gq.z, wf.w))), 0.f);
            hv[j] = (short)f2bs(h);
        }
        *(bf16x8*)&Hs[sp*128 + ((o ^ (sp & 7)) * 8)] = hv;
    }
}

#define MFMA_TILE(acc, afrag, Hs, lg, lr)                                             \
    _Pragma("unroll")                                                                 \
    for (int ks = 0; ks < 4; ++ks) {                                                  \
        _Pragma("unroll")                                                             \
        for (int pt = 0; pt < 8; ++pt) {                                              \
            const int p = 16*pt + lr;                                                 \
            const bf16x8 bf = *(const bf16x8*)&Hs[p*128 + (((4*ks + lg) ^ (lr & 7)) * 8)]; \
            acc[0][pt] = __builtin_amdgcn_mfma_f32_16x16x32_bf16(afrag[0][ks], bf, acc[0][pt], 0, 0, 0); \
            acc[1][pt] = __builtin_amdgcn_mfma_f32_16x16x32_bf16(afrag[1][ks], bf, acc[1][pt], 0, 0, 0); \
        }                                                                             \
    }

// ---------------------------------------------------------------------------
// Pass 1: conv2 stats only (no y2 store).
__global__ __launch_bounds__(256) void conv2stats_kernel(
    const float4* __restrict__ g4, const float* __restrict__ Wf,
    const float* __restrict__ ab, const float* __restrict__ bias,
    double* __restrict__ stats)
{
    __shared__ __align__(16) short Hs[128*128];
    const int tid = threadIdx.x;
    const int p0g = blockIdx.x * 128;
    const int w  = tid >> 6, ln = tid & 63;
    const int lg = ln >> 4, lr = ln & 15;

    bf16x8 afrag[2][4];
    load_afrag(afrag, Wf, w, lg, lr);
    stage_h1(Hs, g4, ab, p0g, w, ln);
    __syncthreads();

    f32x4 acc[2][8];
    #pragma unroll
    for (int i = 0; i < 2; ++i)
        #pragma unroll
        for (int j = 0; j < 8; ++j) acc[i][j] = (f32x4){0.f,0.f,0.f,0.f};
    MFMA_TILE(acc, afrag, Hs, lg, lr);

    const int bank = blockIdx.x & (NBANK-1);
    #pragma unroll
    for (int dtl = 0; dtl < 2; ++dtl) {
        #pragma unroll
        for (int r = 0; r < 4; ++r) {
            const int d = 32*w + 16*dtl + 4*lg + r;
            const float bb = bias[d];
            float v[8];
            #pragma unroll
            for (int pt = 0; pt < 8; ++pt) v[pt] = acc[dtl][pt][r] + bb;
            float s1 = ((v[0]+v[1])+(v[2]+v[3])) + ((v[4]+v[5])+(v[6]+v[7]));
            float s2 = ((v[0]*v[0]+v[1]*v[1])+(v[2]*v[2]+v[3]*v[3]))
                     + ((v[4]*v[4]+v[5]*v[5])+(v[6]*v[6]+v[7]*v[7]));
            s1 += dppf<DPP_XOR1>(s1);  s2 += dppf<DPP_XOR1>(s2);
            s1 += dppf<DPP_XOR2>(s1);  s2 += dppf<DPP_XOR2>(s2);
            s1 += dppf<DPP_HALFM>(s1); s2 += dppf<DPP_HALFM>(s2);
            s1 += dppf<DPP_MIRROR>(s1); s2 += dppf<DPP_MIRROR>(s2);
            if (lr == 0) {
                atomAddD(&stats[I_S2 + bank*256 + d], (double)s1);
                atomAddD(&stats[I_S2 + bank*256 + 128 + d], (double)s2);
            }
        }
    }
}

// ---------------------------------------------------------------------------
// Pass 2: fused conv2 (recompute, bit-identical) -> BN2+ReLU in LDS -> conv3
// -> stats3 + minmax -> ymm.  y2 never touches global memory.
__global__ __launch_bounds__(256) void convfused_kernel(
    const float4* __restrict__ g4, const float* __restrict__ W2f,
    const float* __restrict__ W3f, const float* __restrict__ ab,
    const float* __restrict__ b2, const float* __restrict__ b3,
    float* __restrict__ ymm, double* __restrict__ stats)
{
    __shared__ __align__(16) short Hs[128*128];
    const int tid = threadIdx.x;
    const int p0g = blockIdx.x * 128;
    const int w  = tid >> 6, ln = tid & 63;
    const int lg = ln >> 4, lr = ln & 15;

    bf16x8 afrag[2][4];
    load_afrag(afrag, W2f, w, lg, lr);
    stage_h1(Hs, g4, ab, p0g, w, ln);
    __syncthreads();

    f32x4 acc[2][8];
    #pragma unroll
    for (int i = 0; i < 2; ++i)
        #pragma unroll
        for (int j = 0; j < 8; ++j) acc[i][j] = (f32x4){0.f,0.f,0.f,0.f};
    MFMA_TILE(acc, afrag, Hs, lg, lr);

    __syncthreads();   // all waves done reading h1 from Hs

    // ---- h2 = relu(a2*(y2+b2)+e2) -> bf16, written back into the same
    //      swizzled [p][c] layout (write swizzle == read swizzle).
    #pragma unroll
    for (int dtl = 0; dtl < 2; ++dtl) {
        const int d0 = 32*w + 16*dtl + 4*lg;
        const float4 bb = *(const float4*)&b2[d0];
        const float4 a2v = *(const float4*)&ab[AB_A2 + d0];
        const float4 e2v = *(const float4*)&ab[AB_E2 + d0];
        const float bbv[4] = {bb.x, bb.y, bb.z, bb.w};
        const float aav[4] = {a2v.x, a2v.y, a2v.z, a2v.w};
        const float eev[4] = {e2v.x, e2v.y, e2v.z, e2v.w};
        const int oct = d0 >> 3, rem = d0 & 7;
        #pragma unroll
        for (int pt = 0; pt < 8; ++pt) {
            const int p = 16*pt + lr;
            bf16x4 pk;
            #pragma unroll
            for (int j = 0; j < 4; ++j) {
                const float y = acc[dtl][pt][j] + bbv[j];
                pk[j] = (short)f2bs(fmaxf(__fmaf_rn(aav[j], y, eev[j]), 0.f));
            }
            *(bf16x4*)&Hs[p*128 + ((oct ^ (p & 7)) * 8 + rem)] = pk;
        }
    }

    load_afrag(afrag, W3f, w, lg, lr);   // W3 fragments (L2-hot)
    #pragma unroll
    for (int i = 0; i < 2; ++i)
        #pragma unroll
        for (int j = 0; j < 8; ++j) acc[i][j] = (f32x4){0.f,0.f,0.f,0.f};
    __syncthreads();   // h2 tile complete

    MFMA_TILE(acc, afrag, Hs, lg, lr);

    // ---- stats3 + minmax -> ymm (r11/r12-proven epilogue)
    const int bank = blockIdx.x & (NBANK-1);
    #pragma unroll
    for (int dtl = 0; dtl < 2; ++dtl) {
        #pragma unroll
        for (int r = 0; r < 4; ++r) {
            const int d = 32*w + 16*dtl + 4*lg + r;
            const float bb = b3[d];
            float v[8];
            #pragma unroll
            for (int pt = 0; pt < 8; ++pt) v[pt] = acc[dtl][pt][r] + bb;

            float s1 = ((v[0]+v[1])+(v[2]+v[3])) + ((v[4]+v[5])+(v[6]+v[7]));
            float s2 = ((v[0]*v[0]+v[1]*v[1])+(v[2]*v[2]+v[3]*v[3]))
                     + ((v[4]*v[4]+v[5]*v[5])+(v[6]*v[6]+v[7]*v[7]));
            s1 += dppf<DPP_XOR1>(s1);  s2 += dppf<DPP_XOR1>(s2);
            s1 += dppf<DPP_XOR2>(s1);  s2 += dppf<DPP_XOR2>(s2);
            s1 += dppf<DPP_HALFM>(s1); s2 += dppf<DPP_HALFM>(s2);
            s1 += dppf<DPP_MIRROR>(s1); s2 += dppf<DPP_MIRROR>(s2);
            if (lr == 0) {
                atomAddD(&stats[I_S3 + bank*256 + d], (double)s1);
                atomAddD(&stats[I_S3 + bank*256 + 128 + d], (double)s2);
            }

            #pragma unroll
            for (int pt = 0; pt < 8; ++pt) {
                float mx = v[pt], mn = v[pt];
                mx = fmaxf(mx, dppf<DPP_XOR1>(mx));  mn = fminf(mn, dppf<DPP_XOR1>(mn));
                mx = fmaxf(mx, dppf<DPP_XOR2>(mx));  mn = fminf(mn, dppf<DPP_XOR2>(mn));
                mx = fmaxf(mx, dppf<DPP_HALFM>(mx)); mn = fminf(mn, dppf<DPP_HALFM>(mn));
                if ((lr & 7) == 0) {
                    const int slot = 2*pt + (lr >> 3);
                    float* yb = ymm + ((size_t)d*NBLK + blockIdx.x)*32;
                    yb[slot]      = mx;
                    yb[16 + slot] = mn;
                }
            }
        }
    }
}

// ---------------------------------------------------------------------------
// Epilogue: out[b,d,n] = relu(a3*(a3>=0 ? max_k : min_k) + e3)
__global__ __launch_bounds__(256) void bn3max_kernel(
    const float* __restrict__ ymm, const float* __restrict__ ab, float* __restrict__ out)
{
    const int idx = blockIdx.x*256 + threadIdx.x;   // over B*DIM*N
    const int n = idx & (N_-1);
    const int d = (idx >> 11) & (DIM-1);
    const int b = idx >> 18;
    const int pt  = b*N_ + n;
    const int blk = pt >> 4;
    const int j   = pt & 15;
    const size_t base = ((size_t)d*NBLK + blk) * 32;
    const float a = ab[AB_A3 + d], e = ab[AB_E3 + d];
    const float mx = ymm[base + j];
    const float mn = ymm[base + 16 + j];
    const float v = (a >= 0.f) ? mx : mn;
    out[idx] = fmaxf(__fmaf_rn(a, v, e), 0.f);
}

// ---------------------------------------------------------------------------
extern "C" void kernel_launch(void* const* d_in, const int* in_sizes, int n_in,
                              void* d_out, int out_size, void* d_ws, size_t ws_size,
                              hipStream_t stream) {
    (void)in_sizes; (void)n_in; (void)out_size; (void)ws_size;
    const float* x   = (const float*)d_in[0];
    const float* W1  = (const float*)d_in[1];
    const float* b1  = (const float*)d_in[2];
    const float* g1  = (const float*)d_in[3];
    const float* be1 = (const float*)d_in[4];
    const float* W2  = (const float*)d_in[5];
    const float* b2  = (const float*)d_in[6];
    const float* g2  = (const float*)d_in[7];
    const float* be2 = (const float*)d_in[8];
    const float* W3  = (const float*)d_in[9];
    const float* b3  = (const float*)d_in[10];
    const float* g3  = (const float*)d_in[11];
    const float* be3 = (const float*)d_in[12];

    float*  out = (float*)d_out;
    char*   ws  = (char*)d_ws;
    float4*         g4  = (float4*)(ws + OFF_G);
    double*         st  = (double*)(ws + OFF_STATS);
    float*          ab  = (float*)(ws + OFF_AB);
    float*          kp  = (float*)(ws + OFF_KPART);
    float*          ymm = (float*)(ws + OFF_YMM);

    knn_group_kernel<<<dim3(128, B_), 1024, 0, stream>>>(x, g4, kp, st);
    finalize1_kernel<<<1, 1024, 0, stream>>>(kp, W1, b1, g1, be1, ab);
    conv2stats_kernel<<<NBLK, 256, 0, stream>>>(g4, W2, ab, b2, st);
    finalize23_kernel<<<1, 128, 0, stream>>>(st, I_S2, g2, be2, ab, AB_A2);
    convfused_kernel<<<NBLK, 256, 0, stream>>>(g4, W2, W3, ab, b2, b3, ymm, st);
    finalize23_kernel<<<1, 128, 0, stream>>>(st, I_S3, g3, be3, ab, AB_A3);
    bn3max_kernel<<<(B_*DIM*N_)/256, 256, 0, stream>>>(ymm, ab, out);
}